// Round 7
// baseline (1755.022 us; speedup 1.0000x reference)
//
#include <hip/hip_runtime.h>
#include <hip/hip_bf16.h>

// VQ-VAE EMA update, MI355X (gfx950).
// x[262144][64] f32, emb[1024][64] f32, ema_dw[1024][64], ema_cs[1024], counter int.
// Outputs flat: quantized_st[16777216], loss[1], new_emb[65536],
//               new_dw_hidden[65536], new_cluster_hidden[1024].
//
// CORRECTNESS MODEL (round 6 evidence): the harness's "np" reference computes the
// distance argmin IN FLOAT32 (OpenBLAS sgemm + numpy pairwise sums), and its f32
// rounding at d ~ 64-130 (ulp 7.6e-6) RESOLVES razor ties. An exact fp64 argmin
// mismatches it (absmax 0.483, identical across two different exact-ish kernels).
// So we bit-replicate np's arithmetic:
//   m_k  = sequential f32 FMA over j=0..63            (BLAS k-loop order)
//   x2,e2 = numpy AVX512 pairwise tree                (4x16 blocks + stride halving)
//   d_k  = fl( fl(x2 + e2_k) - 2*m_k )                (fmaf(-2,m,t): 2m exact)
//   argmin: strict < scan (first-min, matches np.argmin)
//   quantized_st = fl(x + fl(q - x))                  (replicates reference STE)

#define NTOK   262144
#define DDIM   64
#define KCODE  1024
#define QELEMS (NTOK * DDIM)

// ws layout (float offsets)
#define WS_COUNTS 0            // 1024
#define WS_DW     1024         // 65536
#define WS_LSUM   66560        // double (2 float slots), byte off 266240 (8B aligned)
#define WS_E2     66562        // 1024
#define WS_CSIZE  67586        // 1024

// numpy pairwise sum of 64 squares, AVX512 order:
// r0..r3 = 16-lane blocks; sum = (r0+r1)+(r2+r3) lanewise; then _mm512_reduce_add_ps
// (halving strides 8,4,2,1). Implemented lanewise-fused: s[L] = (q[L]+q[L+16]) + (q[L+32]+q[L+48]).
template <typename F>
__device__ __forceinline__ float np_sumsq64(F ld)
{
    float s[16];
    #pragma unroll
    for (int L = 0; L < 16; ++L) {
        const float a = ld(L),      b = ld(L + 16);
        const float c = ld(L + 32), d = ld(L + 48);
        s[L] = __fadd_rn(__fadd_rn(__fmul_rn(a, a), __fmul_rn(b, b)),
                         __fadd_rn(__fmul_rn(c, c), __fmul_rn(d, d)));
    }
    float h1[8];
    #pragma unroll
    for (int L = 0; L < 8; ++L) h1[L] = __fadd_rn(s[L], s[L + 8]);
    float h2[4];
    #pragma unroll
    for (int L = 0; L < 4; ++L) h2[L] = __fadd_rn(h1[L], h1[L + 4]);
    const float h3a = __fadd_rn(h2[0], h2[2]);
    const float h3b = __fadd_rn(h2[1], h2[3]);
    return __fadd_rn(h3a, h3b);
}

__global__ __launch_bounds__(1024) void vq_prep(
    const float* __restrict__ emb, float* __restrict__ counts,
    float* __restrict__ dw, double* __restrict__ lsum, float* __restrict__ e2)
{
    const int b = blockIdx.x, t = threadIdx.x;
    if (b < 64) {
        dw[b * 1024 + t] = 0.0f;
    } else if (b == 64) {
        counts[t] = 0.0f;
        if (t == 0) lsum[0] = 0.0;
    } else { // b == 65: per-code squared norm, numpy-pairwise order
        const float* __restrict__ ek = emb + (t << 6);
        e2[t] = np_sumsq64([&](int j) { return ek[j]; });
    }
}

__global__ __launch_bounds__(256) void vq_main(
    const float* __restrict__ x, const float* __restrict__ emb,
    const float* __restrict__ e2, float* __restrict__ qout,
    float* __restrict__ counts, float* __restrict__ dw, double* __restrict__ lsum)
{
    const int tid = threadIdx.x;
    const long row = (long)blockIdx.x * 256 + tid;    // token id, one per lane
    const float* __restrict__ xrow = x + row * DDIM;

    // own row -> 64 VGPRs (statically indexed everywhere; never spilled)
    float xr[64];
    #pragma unroll
    for (int j = 0; j < 16; ++j) {
        const float4 v = ((const float4*)xrow)[j];
        xr[4*j+0] = v.x; xr[4*j+1] = v.y; xr[4*j+2] = v.z; xr[4*j+3] = v.w;
    }

    // ||x||^2 in numpy-pairwise order (enters every d_k before the final subtract)
    const float x2 = np_sumsq64([&](int j) { return xr[j]; });

    // ---- f32 scan replicating np:  d_k = fl( fl(x2 + e2k) - 2*m_k ) ----
    // m_k: sequential FMA chain (BLAS sgemm k-loop order). Chain latency is hidden
    // by 4 waves/SIMD occupancy (issue 136 cyc/code < 4x interleave).
    float best = 3.4e38f;
    int bidx = 0;
    for (int k = 0; k < KCODE; ++k) {
        const int kk = __builtin_amdgcn_readfirstlane(k);     // force s_load path
        const float* __restrict__ ek = emb + (kk << 6);
        float m = 0.0f;
        #pragma unroll
        for (int j = 0; j < 64; ++j) m = fmaf(xr[j], ek[j], m);
        const float t = __fadd_rn(x2, e2[kk]);                // fl(x2 + e2k)
        const float d = fmaf(-2.0f, m, t);                    // fl(t - 2m), 2m exact
        if (d < best) { best = d; bidx = k; }                 // strict < = first-min
    }

    // ---- gather chosen code; quantized_st = fl(x + fl(q - x)); f32-diff loss ----
    const float* __restrict__ eb = emb + (bidx << 6);
    float4* __restrict__ qg = (float4*)(qout + row * DDIM);
    double lacc = 0.0;
    #pragma unroll
    for (int j = 0; j < 16; ++j) {
        const float4 qv = ((const float4*)eb)[j];
        float4 st;
        const float d0 = __fsub_rn(xr[4*j+0], qv.x);   // fl(x - q), as np computes
        const float d1 = __fsub_rn(xr[4*j+1], qv.y);
        const float d2 = __fsub_rn(xr[4*j+2], qv.z);
        const float d3 = __fsub_rn(xr[4*j+3], qv.w);
        st.x = __fsub_rn(xr[4*j+0], d0);               // fl(x - fl(x-q)) == fl(x + fl(q-x))
        st.y = __fsub_rn(xr[4*j+1], d1);
        st.z = __fsub_rn(xr[4*j+2], d2);
        st.w = __fsub_rn(xr[4*j+3], d3);
        qg[j] = st;
        lacc = fma((double)d0, (double)d0, lacc);
        lacc = fma((double)d1, (double)d1, lacc);
        lacc = fma((double)d2, (double)d2, lacc);
        lacc = fma((double)d3, (double)d3, lacc);
    }

    // ---- segment sums via global atomics ----
    float* dwrow = dw + (bidx << 6);
    #pragma unroll
    for (int c = 0; c < DDIM; ++c) atomicAdd(&dwrow[c], xr[c]);
    atomicAdd(&counts[bidx], 1.0f);

    // ---- loss: wave reduce (f64) then one atomic per wave ----
    #pragma unroll
    for (int off = 32; off; off >>= 1) lacc += __shfl_down(lacc, off, 64);
    if ((tid & 63) == 0) atomicAdd(lsum, lacc);
}

__global__ __launch_bounds__(1024) void vq_cluster(
    const float* __restrict__ counts, const float* __restrict__ ech,
    const int* __restrict__ counter, const double* __restrict__ lsum,
    float* __restrict__ nch_out, float* __restrict__ loss_out,
    float* __restrict__ csize)
{
    __shared__ float red[1024];
    const int t = threadIdx.x;
    const int step = counter[0] + 1;
    const float bc = (float)(1.0 - pow(0.99, (double)step));
    const float omd = 0.01f;                       // fl32(1.0 - DECAY)

    const float cnt = counts[t];
    const float ch = ech[t];
    const float nch = __fsub_rn(ch, __fmul_rn(__fsub_rn(ch, cnt), omd));
    nch_out[t] = nch;
    const float avg = nch / bc;
    red[t] = avg;
    __syncthreads();
    for (int s = 512; s > 0; s >>= 1) {
        if (t < s) red[t] += red[t + s];
        __syncthreads();
    }
    const float n = red[0];
    csize[t] = (avg + 1e-5f) / (n + 1024.0f * 1e-5f) * n;   // Laplace smoothing, np op order
    if (t == 0) loss_out[0] = 0.25f * (float)(lsum[0] / (double)QELEMS);
}

__global__ __launch_bounds__(1024) void vq_emb(
    const float* __restrict__ dw, const float* __restrict__ edh,
    const int* __restrict__ counter, const float* __restrict__ csize,
    float* __restrict__ dwh_out, float* __restrict__ emb_out)
{
    const int i = blockIdx.x * 1024 + threadIdx.x;   // 0..65535
    const int step = counter[0] + 1;
    const float bc = (float)(1.0 - pow(0.99, (double)step));
    const float omd = 0.01f;
    const float dwv = dw[i];
    const float eh = edh[i];
    const float ndw = __fsub_rn(eh, __fmul_rn(__fsub_rn(eh, dwv), omd));
    dwh_out[i] = ndw;
    const float avg = ndw / bc;
    emb_out[i] = avg / csize[i >> 6];
}

extern "C" void kernel_launch(void* const* d_in, const int* in_sizes, int n_in,
                              void* d_out, int out_size, void* d_ws, size_t ws_size,
                              hipStream_t stream)
{
    const float* x   = (const float*)d_in[0];
    const float* emb = (const float*)d_in[1];
    const float* edh = (const float*)d_in[2];
    const float* ech = (const float*)d_in[3];
    const int* counter = (const int*)d_in[4];

    float* out      = (float*)d_out;
    float* q_out    = out;
    float* loss_out = out + QELEMS;
    float* emb_out  = loss_out + 1;
    float* dwh_out  = emb_out + KCODE * DDIM;
    float* nch_out  = dwh_out + KCODE * DDIM;

    float* ws      = (float*)d_ws;
    float* counts  = ws + WS_COUNTS;
    float* dw      = ws + WS_DW;
    double* lsum   = (double*)(ws + WS_LSUM);
    float* e2      = ws + WS_E2;
    float* csize   = ws + WS_CSIZE;

    hipLaunchKernelGGL(vq_prep,    dim3(66),   dim3(1024), 0, stream, emb, counts, dw, lsum, e2);
    hipLaunchKernelGGL(vq_main,    dim3(1024), dim3(256),  0, stream, x, emb, e2, q_out, counts, dw, lsum);
    hipLaunchKernelGGL(vq_cluster, dim3(1),    dim3(1024), 0, stream, counts, ech, counter, lsum, nch_out, loss_out, csize);
    hipLaunchKernelGGL(vq_emb,     dim3(64),   dim3(1024), 0, stream, dw, edh, counter, csize, dwh_out, emb_out);
}

// Round 12
// 802.085 us; speedup vs baseline: 2.1881x; 2.1881x over previous
//
#include <hip/hip_runtime.h>
#include <hip/hip_bf16.h>

// VQ-VAE EMA update, MI355X (gfx950).
// x[262144][64] f32, emb[1024][64] f32, ema_dw[1024][64], ema_cs[1024], counter int.
// Outputs flat: quantized_st[16777216], loss[1], new_emb[65536],
//               new_dw_hidden[65536], new_cluster_hidden[1024].
//
// CORRECTNESS MODEL (verified round 7, PASS incl. determinism tripwires): the
// harness "np" reference computes the distance argmin IN FLOAT32:
//   m_k  = sequential f32 FMA over j=0..63            (BLAS k-loop order)
//   x2,e2 = numpy AVX512 pairwise tree
//   d_k  = fl( fl(x2 + e2_k) - 2*m_k ),  argmin = strict-< first-min scan
// ROUND 11 LESSON: a coarse-scan + tau-rescan hybrid produced DIFFERENT outputs
// across calls (first call passed, replays diverged). Removed. This kernel runs
// the bit-exact-np scan for EVERY token, with ILP across 2 adjacent codes
// (2 independent sequential chains; dep-gap 4cyc == FMA latency -> issue-bound)
// instead of round 7's single latency-bound 64-deep chain.
// Epilogue: transposed (lane=dim) so q-store / x-reload / dw-atomics are
// coalesced (round 7 counters: WRITE_SIZE 640MB from 64-cacheline atomics).

#define NTOK   262144
#define DDIM   64
#define KCODE  1024
#define QELEMS (NTOK * DDIM)

// ws layout (float offsets)
#define WS_COUNTS 0            // 1024
#define WS_DW     1024         // 65536
#define WS_LSUM   66560        // double (2 float slots), byte off 266240 (8B aligned)
#define WS_E2     66562        // 1024
#define WS_CSIZE  67586        // 1024

// numpy pairwise sum of 64 squares, AVX512 order (verified round 7).
template <typename F>
__device__ __forceinline__ float np_sumsq64(F ld)
{
    float s[16];
    #pragma unroll
    for (int L = 0; L < 16; ++L) {
        const float a = ld(L),      b = ld(L + 16);
        const float c = ld(L + 32), d = ld(L + 48);
        s[L] = __fadd_rn(__fadd_rn(__fmul_rn(a, a), __fmul_rn(b, b)),
                         __fadd_rn(__fmul_rn(c, c), __fmul_rn(d, d)));
    }
    float h1[8];
    #pragma unroll
    for (int L = 0; L < 8; ++L) h1[L] = __fadd_rn(s[L], s[L + 8]);
    float h2[4];
    #pragma unroll
    for (int L = 0; L < 4; ++L) h2[L] = __fadd_rn(h1[L], h1[L + 4]);
    return __fadd_rn(__fadd_rn(h2[0], h2[2]), __fadd_rn(h2[1], h2[3]));
}

__global__ __launch_bounds__(1024) void vq_prep(
    const float* __restrict__ emb, float* __restrict__ counts,
    float* __restrict__ dw, double* __restrict__ lsum, float* __restrict__ e2)
{
    const int b = blockIdx.x, t = threadIdx.x;
    if (b < 64) {
        dw[b * 1024 + t] = 0.0f;
    } else if (b == 64) {
        counts[t] = 0.0f;
        if (t == 0) lsum[0] = 0.0;
    } else { // b == 65: per-code squared norm, numpy-pairwise order
        const float* __restrict__ ek = emb + (t << 6);
        e2[t] = np_sumsq64([&](int j) { return ek[j]; });
    }
}

__global__ __launch_bounds__(256, 4) void vq_main(
    const float* __restrict__ x, const float* __restrict__ emb,
    const float* __restrict__ e2, float* __restrict__ qout,
    float* __restrict__ counts, float* __restrict__ dw, double* __restrict__ lsum)
{
    __shared__ int sbidx[256];
    const int tid = threadIdx.x;
    const long row = (long)blockIdx.x * 256 + tid;    // token id, one per lane
    const float* __restrict__ xrow = x + row * DDIM;

    // own row -> 64 VGPRs (statically indexed everywhere)
    float xr[64];
    #pragma unroll
    for (int j = 0; j < 16; ++j) {
        const float4 v = ((const float4*)xrow)[j];
        xr[4*j+0] = v.x; xr[4*j+1] = v.y; xr[4*j+2] = v.z; xr[4*j+3] = v.w;
    }

    // ||x||^2 in numpy-pairwise order (enters every d_k)
    const float x2 = np_sumsq64([&](int j) { return xr[j]; });

    // ---- bit-exact-np scan, 2 codes per iteration (2 independent seq chains).
    // Codes k and k+1 are adjacent rows -> one contiguous 512B s_load stream.
    float best = 3.4e38f;
    int bidx = 0;
    for (int k = 0; k < KCODE; k += 2) {
        const int kk = __builtin_amdgcn_readfirstlane(k);     // force s_load path
        const float* __restrict__ ea = emb + (kk << 6);
        const float* __restrict__ eb = ea + DDIM;
        float ma = 0.0f, mb = 0.0f;
        #pragma unroll
        for (int j = 0; j < 64; ++j) {                        // np sequential order per code
            ma = fmaf(xr[j], ea[j], ma);
            mb = fmaf(xr[j], eb[j], mb);
        }
        const float da = fmaf(-2.0f, ma, __fadd_rn(x2, e2[kk]));     // fl(fl(x2+e2)-2m)
        const float db = fmaf(-2.0f, mb, __fadd_rn(x2, e2[kk + 1]));
        if (da < best) { best = da; bidx = kk; }              // strict < = first-min,
        if (db < best) { best = db; bidx = kk + 1; }          // k checked before k+1
    }

    sbidx[tid] = bidx;
    atomicAdd(&counts[bidx], 1.0f);
    __syncthreads();

    // ---- transposed epilogue: lane = dim, walk this wave's 64 tokens.
    // x reload / q store / dw atomic all coalesced (256B row per instruction).
    const int wave = tid >> 6, lane = tid & 63;
    const long tbase = (long)blockIdx.x * 256 + (wave << 6);
    double lacc = 0.0;
    for (int t = 0; t < 64; ++t) {
        const int bt = __builtin_amdgcn_readfirstlane(sbidx[(wave << 6) + t]);
        const float xv = x[(tbase + t) * DDIM + lane];
        const float qv = emb[(bt << 6) + lane];
        const float dd = __fsub_rn(xv, qv);                  // fl(x - q), np order
        qout[(tbase + t) * DDIM + lane] = __fsub_rn(xv, dd); // fl(x - fl(x-q)) == STE
        lacc = fma((double)dd, (double)dd, lacc);
        atomicAdd(&dw[(bt << 6) + lane], xv);
    }

    // ---- loss: wave reduce (f64) then one atomic per wave ----
    #pragma unroll
    for (int off = 32; off; off >>= 1) lacc += __shfl_down(lacc, off, 64);
    if (lane == 0) atomicAdd(lsum, lacc);
}

__global__ __launch_bounds__(1024) void vq_cluster(
    const float* __restrict__ counts, const float* __restrict__ ech,
    const int* __restrict__ counter, const double* __restrict__ lsum,
    float* __restrict__ nch_out, float* __restrict__ loss_out,
    float* __restrict__ csize)
{
    __shared__ float red[1024];
    const int t = threadIdx.x;
    const int step = counter[0] + 1;
    const float bc = (float)(1.0 - pow(0.99, (double)step));
    const float omd = 0.01f;

    const float cnt = counts[t];
    const float ch = ech[t];
    const float nch = __fsub_rn(ch, __fmul_rn(__fsub_rn(ch, cnt), omd));
    nch_out[t] = nch;
    const float avg = nch / bc;
    red[t] = avg;
    __syncthreads();
    for (int s = 512; s > 0; s >>= 1) {
        if (t < s) red[t] += red[t + s];
        __syncthreads();
    }
    const float n = red[0];
    csize[t] = (avg + 1e-5f) / (n + 1024.0f * 1e-5f) * n;
    if (t == 0) loss_out[0] = 0.25f * (float)(lsum[0] / (double)QELEMS);
}

__global__ __launch_bounds__(1024) void vq_emb(
    const float* __restrict__ dw, const float* __restrict__ edh,
    const int* __restrict__ counter, const float* __restrict__ csize,
    float* __restrict__ dwh_out, float* __restrict__ emb_out)
{
    const int i = blockIdx.x * 1024 + threadIdx.x;   // 0..65535
    const int step = counter[0] + 1;
    const float bc = (float)(1.0 - pow(0.99, (double)step));
    const float omd = 0.01f;
    const float dwv = dw[i];
    const float eh = edh[i];
    const float ndw = __fsub_rn(eh, __fmul_rn(__fsub_rn(eh, dwv), omd));
    dwh_out[i] = ndw;
    const float avg = ndw / bc;
    emb_out[i] = avg / csize[i >> 6];
}

extern "C" void kernel_launch(void* const* d_in, const int* in_sizes, int n_in,
                              void* d_out, int out_size, void* d_ws, size_t ws_size,
                              hipStream_t stream)
{
    const float* x   = (const float*)d_in[0];
    const float* emb = (const float*)d_in[1];
    const float* edh = (const float*)d_in[2];
    const float* ech = (const float*)d_in[3];
    const int* counter = (const int*)d_in[4];

    float* out      = (float*)d_out;
    float* q_out    = out;
    float* loss_out = out + QELEMS;
    float* emb_out  = loss_out + 1;
    float* dwh_out  = emb_out + KCODE * DDIM;
    float* nch_out  = dwh_out + KCODE * DDIM;

    float* ws      = (float*)d_ws;
    float* counts  = ws + WS_COUNTS;
    float* dw      = ws + WS_DW;
    double* lsum   = (double*)(ws + WS_LSUM);
    float* e2      = ws + WS_E2;
    float* csize   = ws + WS_CSIZE;

    hipLaunchKernelGGL(vq_prep,    dim3(66),   dim3(1024), 0, stream, emb, counts, dw, lsum, e2);
    hipLaunchKernelGGL(vq_main,    dim3(1024), dim3(256),  0, stream, x, emb, e2, q_out, counts, dw, lsum);
    hipLaunchKernelGGL(vq_cluster, dim3(1),    dim3(1024), 0, stream, counts, ech, counter, lsum, nch_out, loss_out, csize);
    hipLaunchKernelGGL(vq_emb,     dim3(64),   dim3(1024), 0, stream, dw, edh, counter, csize, dwh_out, emb_out);
}